// Round 8
// baseline (98.323 us; speedup 1.0000x reference)
//
#include <hip/hip_runtime.h>

// VQ color lookup, round 18: scalar-FMA probe, de-risked (no inline asm).
// R17 post-mortem: core-dump abort, no absmax -> runtime/alloc failure,
// not a perf datum. R17 kept four 16-wide "=s" asm tuples + (256,8)'s
// 32-VGPR cap while extracting all 16 lanes as scalars; this round deletes
// every exotic element: NO inline asm, plain C++ loads from g_pairs
// (wave-uniform address -> compiler emits its own pipelined s_loads; R12
// proved delivery mechanism is perf-neutral anyway), launch_bounds (256,4)
// (128-VGPR headroom, known-safe R10-R16).
// Theory under test (from R17): VOP3P packed-f32 issues at 8 cyc/wave64 on
// gfx950 (achieved-FLOPs 46 TF ~ half of m07's 103 TF scalar rate; R10's
// 53us matches an 8-cyc census exactly) -> pk gave zero throughput over
// scalar while the asm blobs blocked scheduling. Scalar census: 160 cyc
// per 4-entry group-step -> ~17us scan floor vs ~30us for pk@8cyc.
// Numerics: scan and resolve use the IDENTICAL fmaf-chain helper
// (contract-off): m=fmaf(nx,z0,hz); m=fmaf(ny,z1,m); m=fmaf(nz,z2,m);
// s=m+cw -- bit-equal to R13/R15/R16 scores by construction.
// Select tree exact, strict < => numpy first-index at group level;
// resolve picks first entry == best within the winning group.

#define KPAL 512
#define HW   65536            // 256*256
#define CHW  (3 * HW)
#define NPIX (8 * HW)         // 524288 pixels
#define NELEM (NPIX * 3)      // 1572864 output color elements
#define PPT   4               // pixels per thread (64 lanes * 4 = 256 px/block)
#define NWAVE 4
#define PAIRS_PER_WAVE (KPAL / 2 / NWAVE)   // 64
#define GROUPS_PER_WAVE (PAIRS_PER_WAVE / 2) // 32 (2 pairs = 4 entries each)

typedef float f2 __attribute__((ext_vector_type(2)));

struct __align__(32) Pair {   // palette entries 2j (lo half) and 2j+1 (hi)
    f2 x, y, z, w;            // x,y,z = NEGATED color; w = 0.5 * ||t||^2
};

__device__ Pair g_pairs[KPAL / 2];          // 8 KB static device memory

// Pack the negated pair table; zero the loss accumulator.
__global__ void prep_kernel(const float* __restrict__ table,
                            float* __restrict__ loss)
{
    const int j = threadIdx.x;            // 0..255
    if (j == 0) *loss = 0.0f;
    const float a0 = table[6 * j + 0], a1 = table[6 * j + 1], a2 = table[6 * j + 2];
    const float b0 = table[6 * j + 3], b1 = table[6 * j + 4], b2 = table[6 * j + 5];
    float aw, bw;
    {
#pragma clang fp contract(off)
        aw = a0 * a0 + a1 * a1 + a2 * a2;
        bw = b0 * b0 + b1 * b1 + b2 * b2;
    }
    Pair p;
    p.x = (f2){-a0, -b0};
    p.y = (f2){-a1, -b1};
    p.z = (f2){-a2, -b2};
    p.w = (f2){0.5f * aw, 0.5f * bw};     // exact
    g_pairs[j] = p;
}

// The ONE score formula (used bitwise-identically in scan and resolve):
//   m = fmaf(nx, z0, hz); m = fmaf(ny, z1, m); m = fmaf(nz, z2, m); s = m + cw
static __device__ __forceinline__ float entry_score(
    float nx, float ny, float nz, float cw,
    float z0, float z1, float z2, float hz)
{
#pragma clang fp contract(off)
    float m = fmaf(nx, z0, hz);
    m = fmaf(ny, z1, m);
    m = fmaf(nz, z2, m);
    return m + cw;
}

__global__ __launch_bounds__(256, 4)
void vq_kernel(const float* __restrict__ z,
               const float* __restrict__ table,
               float* __restrict__ out,
               float* __restrict__ loss)
{
    __shared__ float cb_best[NWAVE][256];   // 4 KB
    __shared__ int   cb_bi[NWAVE][256];     // 4 KB
    __shared__ float wsum[NWAVE];
    const Pair* __restrict__ pairs = g_pairs;
    const int t = threadIdx.x;
    const int w = t >> 6, lane = t & 63;
    const int wu = __builtin_amdgcn_readfirstlane(w);   // wave-uniform SGPR

    // Block covers 256 consecutive pixels; all 4 waves process the same px.
    const int blockbase = blockIdx.x * 256;
    const int b  = blockbase >> 16;           // blocks never straddle batch
    const int p0 = blockbase & (HW - 1);
    const int base0 = b * CHW + p0 + lane;    // pixel i at base0 + 64*i

    float Z0[PPT], Z1[PPT], Z2[PPT], HZ[PPT];
#pragma unroll
    for (int i = 0; i < PPT; ++i) {
        const int base = base0 + 64 * i;
        const float z0 = z[base];
        const float z1 = z[base + HW];
        const float z2 = z[base + 2 * HW];
        float zs;
        {
#pragma clang fp contract(off)
            zs = z0 * z0 + z1 * z1 + z2 * z2;
        }
        Z0[i] = z0; Z1[i] = z1; Z2[i] = z2;
        HZ[i] = 0.5f * zs;                    // exact halve
    }

    float best[PPT];
    int   bg[PPT];                            // global GROUP index (4 entries)
#pragma unroll
    for (int i = 0; i < PPT; ++i) { best[i] = 3.4e38f; bg[i] = wu * GROUPS_PER_WAVE; }

    // Wave w scans its palette quarter, 2 pairs (= one 4-entry group) per
    // step. pairs + uniform index -> compiler emits pipelined s_loads.
    const int pb2 = wu * PAIRS_PER_WAVE;      // first pair of this quarter

#pragma unroll 2
    for (int g = 0; g < GROUPS_PER_WAVE; ++g) {
        const Pair pa = pairs[pb2 + 2 * g];
        const Pair pbb = pairs[pb2 + 2 * g + 1];
        const int gv = wu * GROUPS_PER_WAVE + g;
#pragma unroll
        for (int i = 0; i < PPT; ++i) {
            const float s0 = entry_score(pa.x.x,  pa.y.x,  pa.z.x,  pa.w.x,
                                         Z0[i], Z1[i], Z2[i], HZ[i]);
            const float s1 = entry_score(pa.x.y,  pa.y.y,  pa.z.y,  pa.w.y,
                                         Z0[i], Z1[i], Z2[i], HZ[i]);
            const float s2 = entry_score(pbb.x.x, pbb.y.x, pbb.z.x, pbb.w.x,
                                         Z0[i], Z1[i], Z2[i], HZ[i]);
            const float s3 = entry_score(pbb.x.y, pbb.y.y, pbb.z.y, pbb.w.y,
                                         Z0[i], Z1[i], Z2[i], HZ[i]);
            const float m1 = fminf(fminf(best[i], s0), s1);   // v_min3
            const float mn = fminf(fminf(m1, s2), s3);        // v_min3
            const bool imp = mn < best[i];
            bg[i] = imp ? gv : bg[i];
            best[i] = mn;
        }
    }

    // Resolve the winning entry within the winning 4-entry group: recompute
    // all 4 scores with the IDENTICAL helper; first == best -> numpy
    // first-index within the group.
#pragma unroll
    for (int i = 0; i < PPT; ++i) {
        const int g = bg[i];
        const Pair ca  = pairs[2 * g];        // per-lane gather, L1-hit (8 KB)
        const Pair cb2 = pairs[2 * g + 1];
        const float s0 = entry_score(ca.x.x,  ca.y.x,  ca.z.x,  ca.w.x,
                                     Z0[i], Z1[i], Z2[i], HZ[i]);
        const float s1 = entry_score(ca.x.y,  ca.y.y,  ca.z.y,  ca.w.y,
                                     Z0[i], Z1[i], Z2[i], HZ[i]);
        const float s2 = entry_score(cb2.x.x, cb2.y.x, cb2.z.x, cb2.w.x,
                                     Z0[i], Z1[i], Z2[i], HZ[i]);
        const int m4 = (s0 == best[i]) ? 0 : (s1 == best[i]) ? 1
                     : (s2 == best[i]) ? 2 : 3;
        cb_best[w][lane + 64 * i] = best[i];
        cb_bi[w][lane + 64 * i]   = 4 * g + m4;
    }
    __syncthreads();

    // Combine quarters (ordered strict < => numpy first-index), write, loss.
    // px p = t was scanned by THIS thread at slot i == w: reuse regs, no z re-read.
    float z0s = Z0[0], z1s = Z1[0], z2s = Z2[0];
    if (w == 1)      { z0s = Z0[1]; z1s = Z1[1]; z2s = Z2[1]; }
    else if (w == 2) { z0s = Z0[2]; z1s = Z1[2]; z2s = Z2[2]; }
    else if (w == 3) { z0s = Z0[3]; z1s = Z1[3]; z2s = Z2[3]; }

    float lsum = 0.0f;
    {
        const int p = t;                      // 0..255 within block
        float bb = cb_best[0][p];
        int   kk = cb_bi[0][p];
#pragma unroll
        for (int ww = 1; ww < NWAVE; ++ww) {
            const float d  = cb_best[ww][p];
            const int   k2 = cb_bi[ww][p];
            if (d < bb) { bb = d; kk = k2; }
        }
        const int base = b * CHW + p0 + p;
        const float c0 = table[3 * kk + 0];
        const float c1 = table[3 * kk + 1];
        const float c2 = table[3 * kk + 2];
        out[base]          = c0;
        out[base + HW]     = c1;
        out[base + 2 * HW] = c2;
        const float e0 = c0 - z0s, e1 = c1 - z1s, e2 = c2 - z2s;
        lsum = e0 * e0 + e1 * e1 + e2 * e2;
    }

    for (int off = 32; off > 0; off >>= 1)
        lsum += __shfl_down(lsum, off);

    if ((t & 63) == 0) wsum[w] = lsum;
    __syncthreads();
    if (t == 0) {
        const float s = wsum[0] + wsum[1] + wsum[2] + wsum[3];
        atomicAdd(loss, s * (11.0f / (float)NELEM));
    }
}

extern "C" void kernel_launch(void* const* d_in, const int* in_sizes, int n_in,
                              void* d_out, int out_size, void* d_ws, size_t ws_size,
                              hipStream_t stream)
{
    const float* z     = (const float*)d_in[0];
    const float* table = (const float*)d_in[1];
    float* out  = (float*)d_out;
    float* loss = out + NELEM;

    prep_kernel<<<1, 256, 0, stream>>>(table, loss);
    vq_kernel<<<NPIX / 256, 256, 0, stream>>>(z, table, out, loss);
}